// Round 3
// baseline (686.227 us; speedup 1.0000x reference)
//
#include <hip/hip_runtime.h>

// BatchSplitFF: DM=1024, NE=16, ES=4 (NES=64 expert pairs), ESZ=64,
// BATCH*SEQ = 8*2048 tokens -> 1024 groups of 16 tokens.
#define DM   1024
#define NES  64
#define ESZ  64
#define NG   1024
#define TOK  16

typedef __bf16 bf16;
typedef __bf16 bf16x4 __attribute__((ext_vector_type(4)));
typedef __bf16 bf16x8 __attribute__((ext_vector_type(8)));
typedef float  f32x4  __attribute__((ext_vector_type(4)));

// ---------------- K0: transpose weights to bf16, MFMA-friendly layouts ----
// f1 [d][es][f] -> f1p bf16 [es][f][d]  (B-operand rows for K2: k=d contiguous)
// f2 [es][f][d] -> f2t bf16 [es][d][f]  (B-operand rows for K3: k=f contiguous)
__global__ __launch_bounds__(256) void k0_transpose(const float* __restrict__ f1,
                                                    const float* __restrict__ f2,
                                                    bf16* __restrict__ f1p,
                                                    bf16* __restrict__ f2t) {
    __shared__ float tile[64 * 65];
    const int es = blockIdx.y, d0 = blockIdx.x * 64, tid = threadIdx.x;
    // ---- f1 tile: tile[d_local][f]
    #pragma unroll
    for (int i = 0; i < 4; ++i) {
        int idx = i * 256 + tid; int r = idx >> 4, c4 = (idx & 15) * 4;
        float4 v = *(const float4*)(f1 + (size_t)(d0 + r) * 4096 + es * 64 + c4);
        tile[r * 65 + c4] = v.x; tile[r * 65 + c4 + 1] = v.y;
        tile[r * 65 + c4 + 2] = v.z; tile[r * 65 + c4 + 3] = v.w;
    }
    __syncthreads();
    #pragma unroll
    for (int i = 0; i < 2; ++i) {
        int idx = i * 256 + tid; int f = idx >> 3, dl0 = (idx & 7) * 8;
        bf16x8 o;
        #pragma unroll
        for (int j = 0; j < 8; ++j) o[j] = (bf16)tile[(dl0 + j) * 65 + f];
        *(bf16x8*)(f1p + (size_t)es * 65536 + f * 1024 + d0 + dl0) = o;
    }
    __syncthreads();
    // ---- f2 tile: tile[f][d_local]
    #pragma unroll
    for (int i = 0; i < 4; ++i) {
        int idx = i * 256 + tid; int r = idx >> 4, c4 = (idx & 15) * 4;
        float4 v = *(const float4*)(f2 + (size_t)es * 65536 + r * 1024 + d0 + c4);
        tile[r * 65 + c4] = v.x; tile[r * 65 + c4 + 1] = v.y;
        tile[r * 65 + c4 + 2] = v.z; tile[r * 65 + c4 + 3] = v.w;
    }
    __syncthreads();
    #pragma unroll
    for (int i = 0; i < 2; ++i) {
        int idx = i * 256 + tid; int dl = idx >> 3, f0 = (idx & 7) * 8;
        bf16x8 o;
        #pragma unroll
        for (int j = 0; j < 8; ++j) o[j] = (bf16)tile[(f0 + j) * 65 + dl];
        *(bf16x8*)(f2t + (size_t)es * 65536 + (size_t)(d0 + dl) * 64 + f0) = o;
    }
}

// ---------------- K1: fp32 logits + argmax + sel nibble-pack ----------------
// 128 thr / 2 waves per group. Wave wq owns t = wq*8 .. wq*8+7. x rows are
// wave-uniform -> scalar (SMEM) loads; ctrl one coalesced 256B load per dl.
// Per-(t,es) accumulation: single fmac chain, dl ascending -> logits are
// BIT-IDENTICAL to the previously passing version (no LDS in hot loop).
__global__ __launch_bounds__(128) void k1_logits(const float* __restrict__ x,
                                                 const float* __restrict__ ctrl,
                                                 int* __restrict__ sel,
                                                 unsigned* __restrict__ selp) {
    __shared__ float sl[TOK * NES];
    __shared__ int   st[NES];
    const int bg  = blockIdx.x;
    const int tid = threadIdx.x;
    const int es  = tid & 63;
    const int wq  = __builtin_amdgcn_readfirstlane(tid >> 6);   // 0 or 1
    const float* xg = x + (size_t)bg * (TOK * DM) + (size_t)wq * 8 * DM;
    const float* cp = ctrl + es;
    float acc[8] = {0.f,0.f,0.f,0.f,0.f,0.f,0.f,0.f};
    #pragma unroll 2
    for (int dl = 0; dl < DM; dl += 4) {
        float c0 = cp[(dl + 0) * 64], c1 = cp[(dl + 1) * 64],
              c2 = cp[(dl + 2) * 64], c3 = cp[(dl + 3) * 64];
        #pragma unroll
        for (int i = 0; i < 8; ++i) {
            const float* xr = xg + i * DM + dl;    // wave-uniform -> s_load
            acc[i] += xr[0] * c0; acc[i] += xr[1] * c1;
            acc[i] += xr[2] * c2; acc[i] += xr[3] * c3;
        }
    }
    #pragma unroll
    for (int i = 0; i < 8; ++i) {
        int t = wq * 8 + i;
        sl[t * NES + es] = acc[i] + (float)t * (1e-6f / 15.f);
    }
    __syncthreads();
    if (tid < NES) {
        float best = -1e30f; int bi = 0;
        #pragma unroll
        for (int t = 0; t < TOK; ++t) {
            float v = sl[t * NES + tid];
            if (v >= best) { best = v; bi = t; }   // >= : later t wins ties
        }
        sel[bg * NES + tid] = bi;
        st[tid] = bi;
    }
    __syncthreads();
    if (tid < 8) {   // pack 8 es per dword, 4-bit each
        unsigned p = 0;
        #pragma unroll
        for (int k = 0; k < 8; ++k) p |= (unsigned)st[tid * 8 + k] << (4 * k);
        selp[bg * 8 + tid] = p;
    }
}

// ---------------- K2: FFN1 (gather + GEMM + bias + relu) ----------------
__global__ __launch_bounds__(256) void k2_ffn1(const float* __restrict__ x,
                                               const bf16* __restrict__ f1p,
                                               const float* __restrict__ bias,
                                               const int* __restrict__ sel,
                                               bf16* __restrict__ inner) {
    __shared__ int  sel_s[128];
    __shared__ __align__(16) bf16 As[128 * 40];
    __shared__ __align__(16) bf16 Bs[64 * 40];
    const int es  = blockIdx.y;
    const int g0  = blockIdx.x * 128;
    const int tid = threadIdx.x;
    if (tid < 128) sel_s[tid] = sel[(g0 + tid) * 64 + es];
    __syncthreads();

    const int w = tid >> 6, l = tid & 63, quad = l >> 4, lr = l & 15;
    int tokrow[4];
    #pragma unroll
    for (int p = 0; p < 4; ++p) {
        int grow = p * 32 + (tid >> 3);
        tokrow[p] = (g0 + grow) * 16 + sel_s[grow];
    }
    const int c4 = (tid & 7) * 4;
    const int bf = tid >> 2, bd = (tid & 3) * 8;
    const bf16* f1es = f1p + (size_t)es * (DM * ESZ);

    f32x4 acc[2][4];
    #pragma unroll
    for (int mt = 0; mt < 2; ++mt)
        #pragma unroll
        for (int nt = 0; nt < 4; ++nt)
            acc[mt][nt] = (f32x4){0.f, 0.f, 0.f, 0.f};

    for (int k0 = 0; k0 < DM; k0 += 32) {
        #pragma unroll
        for (int p = 0; p < 4; ++p) {
            int grow = p * 32 + (tid >> 3);
            float4 v = *(const float4*)(x + (size_t)tokrow[p] * DM + k0 + c4);
            bf16x4 ob = {(bf16)v.x, (bf16)v.y, (bf16)v.z, (bf16)v.w};
            *(bf16x4*)(As + grow * 40 + c4) = ob;
        }
        {
            bf16x8 v = *(const bf16x8*)(f1es + bf * 1024 + k0 + bd);
            *(bf16x8*)(Bs + bf * 40 + bd) = v;
        }
        __syncthreads();
        bf16x8 av[2], bv[4];
        #pragma unroll
        for (int mt = 0; mt < 2; ++mt)
            av[mt] = *(const bf16x8*)(As + (w * 32 + mt * 16 + lr) * 40 + quad * 8);
        #pragma unroll
        for (int nt = 0; nt < 4; ++nt)
            bv[nt] = *(const bf16x8*)(Bs + (nt * 16 + lr) * 40 + quad * 8);
        #pragma unroll
        for (int mt = 0; mt < 2; ++mt)
            #pragma unroll
            for (int nt = 0; nt < 4; ++nt)
                acc[mt][nt] = __builtin_amdgcn_mfma_f32_16x16x32_bf16(
                    av[mt], bv[nt], acc[mt][nt], 0, 0, 0);
        __syncthreads();
    }
    bf16* innes = inner + (size_t)es * (NG * ESZ);
    #pragma unroll
    for (int mt = 0; mt < 2; ++mt)
        #pragma unroll
        for (int nt = 0; nt < 4; ++nt) {
            int f = nt * 16 + lr;
            float b = bias[es * 64 + f];
            #pragma unroll
            for (int r = 0; r < 4; ++r) {
                int grow = w * 32 + mt * 16 + quad * 4 + r;
                float v = acc[mt][nt][r] + b;
                v = v > 0.f ? v : 0.f;
                innes[(size_t)(g0 + grow) * 64 + f] = (bf16)v;
            }
        }
}

// ---------------- K3: FFN2 + un-permute scatter ----------------
// Block = 32g x 32d tile, 256 thr / 4 waves. Wave w owns es in [w*16,w*16+16)
// and the FULL tile via a 2x2 MFMA cell block (loads/MFMA = 1). Scatter is
// ds_add_f32 (atomicAdd on LDS) into a shared token-space fp32 accumulator
// (races between waves are atomic-safe). sel comes as 4-bit nibbles held in
// registers for the entire loop (zero per-es sel loads).
__global__ __launch_bounds__(256) void k3_ffn2(const bf16* __restrict__ inner,
                                               const bf16* __restrict__ f2t,
                                               const unsigned* __restrict__ selp,
                                               float* __restrict__ out) {
    __shared__ float accs[512 * 32];   // [gl*16+t][swizzled d-col], 64KB
    const int d0  = blockIdx.x * 32;
    const int g0  = blockIdx.y * 32;
    const int tid = threadIdx.x;
    const int w = tid >> 6, l = tid & 63, quad = l >> 4, lr = l & 15;

    // selpack: 8 g-rows x (16 es of this wave = 2 dwords)
    uint2 sp[2][4];
    #pragma unroll
    for (int mt = 0; mt < 2; ++mt)
        #pragma unroll
        for (int r = 0; r < 4; ++r) {
            int gl = mt * 16 + quad * 4 + r;
            sp[mt][r] = *(const uint2*)(selp + (size_t)(g0 + gl) * 8 + w * 2);
        }

    #pragma unroll
    for (int i = 0; i < 16; ++i)
        ((float4*)accs)[i * 256 + tid] = (float4){0.f, 0.f, 0.f, 0.f};

    const size_t esoff = (size_t)(w * 16) * 65536;
    const bf16* pa[2];
    const bf16* pb[2];
    pa[0] = inner + esoff + (size_t)(g0 + lr) * 64 + quad * 8;
    pa[1] = pa[0] + 16 * 64;
    pb[0] = f2t + esoff + (size_t)(d0 + lr) * 64 + quad * 8;
    pb[1] = pb[0] + 16 * 64;

    bf16x8 A[2][2], B[2][2];
    #pragma unroll
    for (int mt = 0; mt < 2; ++mt) {
        A[mt][0] = *(const bf16x8*)(pa[mt]);
        A[mt][1] = *(const bf16x8*)(pa[mt] + 32);
        B[mt][0] = *(const bf16x8*)(pb[mt]);
        B[mt][1] = *(const bf16x8*)(pb[mt] + 32);
    }
    __syncthreads();   // accs zero-init visible

    #pragma unroll
    for (int i = 0; i < 16; ++i) {
        const int inext = (i < 15) ? i + 1 : 15;   // compile-time
        bf16x8 An[2][2], Bn[2][2];
        #pragma unroll
        for (int mt = 0; mt < 2; ++mt) {
            An[mt][0] = *(const bf16x8*)(pa[mt] + (size_t)inext * 65536);
            An[mt][1] = *(const bf16x8*)(pa[mt] + (size_t)inext * 65536 + 32);
            Bn[mt][0] = *(const bf16x8*)(pb[mt] + (size_t)inext * 65536);
            Bn[mt][1] = *(const bf16x8*)(pb[mt] + (size_t)inext * 65536 + 32);
        }
        f32x4 acc[2][2];
        #pragma unroll
        for (int mt = 0; mt < 2; ++mt)
            #pragma unroll
            for (int nt = 0; nt < 2; ++nt) {
                f32x4 z = {0.f, 0.f, 0.f, 0.f};
                z = __builtin_amdgcn_mfma_f32_16x16x32_bf16(A[mt][0], B[nt][0], z, 0, 0, 0);
                acc[mt][nt] = __builtin_amdgcn_mfma_f32_16x16x32_bf16(A[mt][1], B[nt][1], z, 0, 0, 0);
            }
        #pragma unroll
        for (int mt = 0; mt < 2; ++mt)
            #pragma unroll
            for (int r = 0; r < 4; ++r) {
                unsigned pw = (i < 8) ? sp[mt][r].x : sp[mt][r].y;  // compile-time sel
                int t  = (pw >> ((i & 7) * 4)) & 15;
                int gl = mt * 16 + quad * 4 + r;
                int base = gl * 512 + t * 32;          // (gl*16+t)*32
                int sw = (t & 7) << 2;
                #pragma unroll
                for (int nt = 0; nt < 2; ++nt) {
                    int col = nt * 16 + lr;
                    atomicAdd(&accs[base + (col ^ sw)], acc[mt][nt][r]);
                }
            }
        #pragma unroll
        for (int mt = 0; mt < 2; ++mt) {
            A[mt][0] = An[mt][0]; A[mt][1] = An[mt][1];
            B[mt][0] = Bn[mt][0]; B[mt][1] = Bn[mt][1];
        }
    }
    __syncthreads();
    // dense write-out (un-swizzle; every output element written exactly once)
    #pragma unroll
    for (int i = 0; i < 16; ++i) {
        int fi = i * 256 + tid;
        int row = fi >> 3, q = fi & 7;
        int scol4 = (q * 4) ^ ((row & 7) << 2);
        float4 v = *(float4*)(accs + row * 32 + scol4);
        *(float4*)(out + (size_t)(g0 * 16 + row) * DM + d0 + q * 4) = v;
    }
}

extern "C" void kernel_launch(void* const* d_in, const int* in_sizes, int n_in,
                              void* d_out, int out_size, void* d_ws, size_t ws_size,
                              hipStream_t stream) {
    const float* x    = (const float*)d_in[0];
    const float* ctrl = (const float*)d_in[1];
    const float* f1   = (const float*)d_in[2];
    const float* f2   = (const float*)d_in[3];
    const float* bias = (const float*)d_in[4];
    float* out = (float*)d_out;

    char* ws = (char*)d_ws;
    bf16*     f1p   = (bf16*)(ws);                  // 8,388,608 B
    bf16*     f2t   = (bf16*)(ws + 8388608);        // 8,388,608 B
    bf16*     inner = (bf16*)(ws + 16777216);       // 8,388,608 B
    int*      sel   = (int*)(ws + 25165824);        //   262,144 B
    unsigned* selp  = (unsigned*)(ws + 25427968);   //    32,768 B

    hipLaunchKernelGGL(k0_transpose, dim3(16, 64), dim3(256), 0, stream, f1, f2, f1p, f2t);
    hipLaunchKernelGGL(k1_logits,    dim3(1024),   dim3(128), 0, stream, x, ctrl, sel, selp);
    hipLaunchKernelGGL(k2_ffn1,      dim3(8, 64),  dim3(256), 0, stream, x, f1p, bias, sel, inner);
    hipLaunchKernelGGL(k3_ffn2,      dim3(32, 32), dim3(256), 0, stream, inner, f2t, selp, out);
}

// Round 4
// 352.688 us; speedup vs baseline: 1.9457x; 1.9457x over previous
//
#include <hip/hip_runtime.h>

// BatchSplitFF: DM=1024, NE=16, ES=4 (NES=64 expert pairs), ESZ=64,
// BATCH*SEQ = 8*2048 tokens -> 1024 groups of 16 tokens.
#define DM   1024
#define NES  64
#define ESZ  64
#define NG   1024
#define TOK  16

typedef __bf16 bf16;
typedef __bf16 bf16x4 __attribute__((ext_vector_type(4)));
typedef __bf16 bf16x8 __attribute__((ext_vector_type(8)));
typedef float  f32x4  __attribute__((ext_vector_type(4)));

// ---------------- K0: transpose weights to bf16, MFMA-friendly layouts ----
// f1 [d][es][f] -> f1p bf16 [es][f][d]   f2 [es][f][d] -> f2t bf16 [es][d][f]
__global__ __launch_bounds__(256) void k0_transpose(const float* __restrict__ f1,
                                                    const float* __restrict__ f2,
                                                    bf16* __restrict__ f1p,
                                                    bf16* __restrict__ f2t) {
    __shared__ float tile[64 * 65];
    const int es = blockIdx.y, d0 = blockIdx.x * 64, tid = threadIdx.x;
    #pragma unroll
    for (int i = 0; i < 4; ++i) {
        int idx = i * 256 + tid; int r = idx >> 4, c4 = (idx & 15) * 4;
        float4 v = *(const float4*)(f1 + (size_t)(d0 + r) * 4096 + es * 64 + c4);
        tile[r * 65 + c4] = v.x; tile[r * 65 + c4 + 1] = v.y;
        tile[r * 65 + c4 + 2] = v.z; tile[r * 65 + c4 + 3] = v.w;
    }
    __syncthreads();
    #pragma unroll
    for (int i = 0; i < 2; ++i) {
        int idx = i * 256 + tid; int f = idx >> 3, dl0 = (idx & 7) * 8;
        bf16x8 o;
        #pragma unroll
        for (int j = 0; j < 8; ++j) o[j] = (bf16)tile[(dl0 + j) * 65 + f];
        *(bf16x8*)(f1p + (size_t)es * 65536 + f * 1024 + d0 + dl0) = o;
    }
    __syncthreads();
    #pragma unroll
    for (int i = 0; i < 4; ++i) {
        int idx = i * 256 + tid; int r = idx >> 4, c4 = (idx & 15) * 4;
        float4 v = *(const float4*)(f2 + (size_t)es * 65536 + r * 1024 + d0 + c4);
        tile[r * 65 + c4] = v.x; tile[r * 65 + c4 + 1] = v.y;
        tile[r * 65 + c4 + 2] = v.z; tile[r * 65 + c4 + 3] = v.w;
    }
    __syncthreads();
    #pragma unroll
    for (int i = 0; i < 2; ++i) {
        int idx = i * 256 + tid; int dl = idx >> 3, f0 = (idx & 7) * 8;
        bf16x8 o;
        #pragma unroll
        for (int j = 0; j < 8; ++j) o[j] = (bf16)tile[(f0 + j) * 65 + dl];
        *(bf16x8*)(f2t + (size_t)es * 65536 + (size_t)(d0 + dl) * 64 + f0) = o;
    }
}

// ---------------- K1: fp32 logits + argmax + sel nibble-pack ----------------
// Round-2 structure; hot loop now uses ds_read_b128 broadcast (4 dl / instr,
// 4x fewer LDS instructions). Per-(t,es) chain: single fmac per term, dl
// ascending -> BIT-IDENTICAL logits to the passing rounds.
__global__ __launch_bounds__(256) void k1_logits(const float* __restrict__ x,
                                                 const float* __restrict__ ctrl,
                                                 int* __restrict__ sel,
                                                 unsigned* __restrict__ selp) {
    __shared__ __align__(16) float xs[TOK * 132];   // row stride 132 (528B, 16B-mult)
    __shared__ float sl[TOK * NES];
    __shared__ int   st[NES];
    const int bg  = blockIdx.x;
    const int tid = threadIdx.x;
    const int es  = tid & 63;
    const int tq  = tid >> 6;            // wave 0..3 -> rows tq*4 .. tq*4+3
    const float* xg = x + (size_t)bg * (TOK * DM);
    const float* cp = ctrl + es;
    float acc[4] = {0.f, 0.f, 0.f, 0.f};
    for (int d0 = 0; d0 < DM; d0 += 128) {
        __syncthreads();
        #pragma unroll
        for (int c = 0; c < 2; ++c) {    // stage 16 x 128 chunk (coalesced)
            int idx = tid + c * 256;
            int tr  = idx >> 5;
            int c4  = (idx & 31) * 4;
            float4 v = *(const float4*)(xg + tr * DM + d0 + c4);
            *(float4*)(xs + tr * 132 + c4) = v;
        }
        __syncthreads();
        #pragma unroll 2
        for (int dl4 = 0; dl4 < 128; dl4 += 4) {
            float4 v0 = *(const float4*)(xs + (tq * 4 + 0) * 132 + dl4);
            float4 v1 = *(const float4*)(xs + (tq * 4 + 1) * 132 + dl4);
            float4 v2 = *(const float4*)(xs + (tq * 4 + 2) * 132 + dl4);
            float4 v3 = *(const float4*)(xs + (tq * 4 + 3) * 132 + dl4);
            float c0 = cp[(size_t)(d0 + dl4 + 0) * 64];
            float c1 = cp[(size_t)(d0 + dl4 + 1) * 64];
            float c2 = cp[(size_t)(d0 + dl4 + 2) * 64];
            float c3 = cp[(size_t)(d0 + dl4 + 3) * 64];
            acc[0] += v0.x * c0; acc[1] += v1.x * c0;
            acc[2] += v2.x * c0; acc[3] += v3.x * c0;
            acc[0] += v0.y * c1; acc[1] += v1.y * c1;
            acc[2] += v2.y * c1; acc[3] += v3.y * c1;
            acc[0] += v0.z * c2; acc[1] += v1.z * c2;
            acc[2] += v2.z * c2; acc[3] += v3.z * c2;
            acc[0] += v0.w * c3; acc[1] += v1.w * c3;
            acc[2] += v2.w * c3; acc[3] += v3.w * c3;
        }
    }
    #pragma unroll
    for (int i = 0; i < 4; ++i) {
        int t = tq * 4 + i;
        sl[t * NES + es] = acc[i] + (float)t * (1e-6f / 15.f);
    }
    __syncthreads();
    if (tid < NES) {
        float best = -1e30f; int bi = 0;
        #pragma unroll
        for (int t = 0; t < TOK; ++t) {
            float v = sl[t * NES + tid];
            if (v >= best) { best = v; bi = t; }   // >= : later t wins ties
        }
        sel[bg * NES + tid] = bi;
        st[tid] = bi;
    }
    __syncthreads();
    if (tid < 8) {   // pack 8 es per dword, 4-bit each
        unsigned p = 0;
        #pragma unroll
        for (int k = 0; k < 8; ++k) p |= (unsigned)st[tid * 8 + k] << (4 * k);
        selp[bg * 8 + tid] = p;
    }
}

// ---------------- K2: FFN1 (gather + GEMM + bias + relu) ----------------
__global__ __launch_bounds__(256) void k2_ffn1(const float* __restrict__ x,
                                               const bf16* __restrict__ f1p,
                                               const float* __restrict__ bias,
                                               const int* __restrict__ sel,
                                               bf16* __restrict__ inner) {
    __shared__ int  sel_s[128];
    __shared__ __align__(16) bf16 As[128 * 40];
    __shared__ __align__(16) bf16 Bs[64 * 40];
    const int es  = blockIdx.y;
    const int g0  = blockIdx.x * 128;
    const int tid = threadIdx.x;
    if (tid < 128) sel_s[tid] = sel[(g0 + tid) * 64 + es];
    __syncthreads();

    const int w = tid >> 6, l = tid & 63, quad = l >> 4, lr = l & 15;
    int tokrow[4];
    #pragma unroll
    for (int p = 0; p < 4; ++p) {
        int grow = p * 32 + (tid >> 3);
        tokrow[p] = (g0 + grow) * 16 + sel_s[grow];
    }
    const int c4 = (tid & 7) * 4;
    const int bf = tid >> 2, bd = (tid & 3) * 8;
    const bf16* f1es = f1p + (size_t)es * (DM * ESZ);

    f32x4 acc[2][4];
    #pragma unroll
    for (int mt = 0; mt < 2; ++mt)
        #pragma unroll
        for (int nt = 0; nt < 4; ++nt)
            acc[mt][nt] = (f32x4){0.f, 0.f, 0.f, 0.f};

    for (int k0 = 0; k0 < DM; k0 += 32) {
        #pragma unroll
        for (int p = 0; p < 4; ++p) {
            int grow = p * 32 + (tid >> 3);
            float4 v = *(const float4*)(x + (size_t)tokrow[p] * DM + k0 + c4);
            bf16x4 ob = {(bf16)v.x, (bf16)v.y, (bf16)v.z, (bf16)v.w};
            *(bf16x4*)(As + grow * 40 + c4) = ob;
        }
        {
            bf16x8 v = *(const bf16x8*)(f1es + bf * 1024 + k0 + bd);
            *(bf16x8*)(Bs + bf * 40 + bd) = v;
        }
        __syncthreads();
        bf16x8 av[2], bv[4];
        #pragma unroll
        for (int mt = 0; mt < 2; ++mt)
            av[mt] = *(const bf16x8*)(As + (w * 32 + mt * 16 + lr) * 40 + quad * 8);
        #pragma unroll
        for (int nt = 0; nt < 4; ++nt)
            bv[nt] = *(const bf16x8*)(Bs + (nt * 16 + lr) * 40 + quad * 8);
        #pragma unroll
        for (int mt = 0; mt < 2; ++mt)
            #pragma unroll
            for (int nt = 0; nt < 4; ++nt)
                acc[mt][nt] = __builtin_amdgcn_mfma_f32_16x16x32_bf16(
                    av[mt], bv[nt], acc[mt][nt], 0, 0, 0);
        __syncthreads();
    }
    bf16* innes = inner + (size_t)es * (NG * ESZ);
    #pragma unroll
    for (int mt = 0; mt < 2; ++mt)
        #pragma unroll
        for (int nt = 0; nt < 4; ++nt) {
            int f = nt * 16 + lr;
            float b = bias[es * 64 + f];
            #pragma unroll
            for (int r = 0; r < 4; ++r) {
                int grow = w * 32 + mt * 16 + quad * 4 + r;
                float v = acc[mt][nt][r] + b;
                v = v > 0.f ? v : 0.f;
                innes[(size_t)(g0 + grow) * 64 + f] = (bf16)v;
            }
        }
}

// ---------------- K3: FFN2 + un-permute scatter ----------------
// Round-2 race-free partition (wave = m-half x n-half -> disjoint LDS rows x
// cols, plain read-add-write, NO atomics). New: sel nibbles preloaded into
// registers for the whole loop; fully-unrolled es-loop with a 4-slot register
// pipeline (loads issued 2 iterations ahead of use) to cover L2/LLC latency.
__global__ __launch_bounds__(256) void k3_ffn2(const bf16* __restrict__ inner,
                                               const bf16* __restrict__ f2t,
                                               const unsigned* __restrict__ selp,
                                               float* __restrict__ out) {
    __shared__ float accs[512 * 32];   // [gl*16+t][swizzled d-col], 64KB
    const int d0  = blockIdx.x * 32;
    const int g0  = blockIdx.y * 32;
    const int tid = threadIdx.x;
    const int w = tid >> 6, l = tid & 63, quad = l >> 4, lr = l & 15;
    const int mh = w >> 1, nh = w & 1;

    // preload sel nibbles: this lane's 4 rows x 64 es (8 dwords per row)
    unsigned sp[4][8];
    #pragma unroll
    for (int r = 0; r < 4; ++r) {
        int gl = mh * 16 + quad * 4 + r;
        uint4 a = *(const uint4*)(selp + (size_t)(g0 + gl) * 8);
        uint4 b = *(const uint4*)(selp + (size_t)(g0 + gl) * 8 + 4);
        sp[r][0] = a.x; sp[r][1] = a.y; sp[r][2] = a.z; sp[r][3] = a.w;
        sp[r][4] = b.x; sp[r][5] = b.y; sp[r][6] = b.z; sp[r][7] = b.w;
    }
    #pragma unroll
    for (int i = 0; i < 16; ++i)
        ((float4*)accs)[i * 256 + tid] = (float4){0.f, 0.f, 0.f, 0.f};

    const bf16* pa = inner + (size_t)(g0 + mh * 16 + lr) * 64 + quad * 8;
    const bf16* pb = f2t   + (size_t)(d0 + nh * 16 + lr) * 64 + quad * 8;

    bf16x8 A[4][2], B[4][2];   // 4 pipeline slots, slot = es & 3
    #pragma unroll
    for (int s = 0; s < 2; ++s) {   // preload es = 0, 1
        const bf16* qa = pa + (size_t)s * 65536;
        const bf16* qb = pb + (size_t)s * 65536;
        A[s][0] = *(const bf16x8*)(qa);
        A[s][1] = *(const bf16x8*)(qa + 32);
        B[s][0] = *(const bf16x8*)(qb);
        B[s][1] = *(const bf16x8*)(qb + 32);
    }
    __syncthreads();   // accs zero-init visible

    #pragma unroll
    for (int es = 0; es < 64; ++es) {
        // prefetch es+2 (es=62,63 read past the 64-es extent but stay inside
        // the workspace allocation; values are never consumed)
        const int lp = (es + 2) & 3;
        const bf16* qa = pa + (size_t)(es + 2) * 65536;
        const bf16* qb = pb + (size_t)(es + 2) * 65536;
        A[lp][0] = *(const bf16x8*)(qa);
        A[lp][1] = *(const bf16x8*)(qa + 32);
        B[lp][0] = *(const bf16x8*)(qb);
        B[lp][1] = *(const bf16x8*)(qb + 32);

        const int s = es & 3;
        f32x4 z = {0.f, 0.f, 0.f, 0.f};
        z = __builtin_amdgcn_mfma_f32_16x16x32_bf16(A[s][0], B[s][0], z, 0, 0, 0);
        z = __builtin_amdgcn_mfma_f32_16x16x32_bf16(A[s][1], B[s][1], z, 0, 0, 0);

        const int dw = es >> 3, sh = (es & 7) * 4;   // compile-time after unroll
        #pragma unroll
        for (int r = 0; r < 4; ++r) {
            int t    = (sp[r][dw] >> sh) & 15;
            int gl   = mh * 16 + quad * 4 + r;
            int scol = (nh * 16 + lr) ^ ((t & 7) << 2);
            accs[(gl * 16 + t) * 32 + scol] += z[r];   // unique owner: no race
        }
    }
    __syncthreads();
    // dense write-out (un-swizzle; every output element written exactly once)
    #pragma unroll
    for (int i = 0; i < 16; ++i) {
        int fi = i * 256 + tid;
        int row = fi >> 3, q = fi & 7;
        int scol4 = (q * 4) ^ ((row & 7) << 2);
        float4 v = *(float4*)(accs + row * 32 + scol4);
        *(float4*)(out + (size_t)(g0 * 16 + row) * DM + d0 + q * 4) = v;
    }
}

extern "C" void kernel_launch(void* const* d_in, const int* in_sizes, int n_in,
                              void* d_out, int out_size, void* d_ws, size_t ws_size,
                              hipStream_t stream) {
    const float* x    = (const float*)d_in[0];
    const float* ctrl = (const float*)d_in[1];
    const float* f1   = (const float*)d_in[2];
    const float* f2   = (const float*)d_in[3];
    const float* bias = (const float*)d_in[4];
    float* out = (float*)d_out;

    char* ws = (char*)d_ws;
    bf16*     f1p   = (bf16*)(ws);                  // 8,388,608 B
    bf16*     f2t   = (bf16*)(ws + 8388608);        // 8,388,608 B
    bf16*     inner = (bf16*)(ws + 16777216);       // 8,388,608 B
    int*      sel   = (int*)(ws + 25165824);        //   262,144 B
    unsigned* selp  = (unsigned*)(ws + 25427968);   //    32,768 B

    hipLaunchKernelGGL(k0_transpose, dim3(16, 64), dim3(256), 0, stream, f1, f2, f1p, f2t);
    hipLaunchKernelGGL(k1_logits,    dim3(1024),   dim3(256), 0, stream, x, ctrl, sel, selp);
    hipLaunchKernelGGL(k2_ffn1,      dim3(8, 64),  dim3(256), 0, stream, x, f1p, bias, sel, inner);
    hipLaunchKernelGGL(k3_ffn2,      dim3(32, 32), dim3(256), 0, stream, inner, f2t, selp, out);
}